// Round 1
// baseline (756.569 us; speedup 1.0000x reference)
//
#include <hip/hip_runtime.h>

// GCN 2-layer forward: out = A( relu(A(X@W1)+b1) @ W2 ) + b2
// where A is sym-normalized adjacency with self loops.
// Strategy: build dest-sorted CSR once (count -> scan -> fill), then each
// layer is GEMM (vector fp32, LDS-tiled) + gather-aggregate (no float atomics).

__global__ __launch_bounds__(256) void init_deg_kernel(int* __restrict__ deg, int n) {
    int i = blockIdx.x * 256 + threadIdx.x;
    if (i < n) deg[i] = 1;   // self loop
}

__global__ __launch_bounds__(256) void count_kernel(const int* __restrict__ col,
                                                    int* __restrict__ deg, int E) {
    int i = blockIdx.x * 256 + threadIdx.x;
    if (i < E) atomicAdd(&deg[col[i]], 1);
}

// Single-block scan over N degree counts -> CSR offsets (excluding self loops),
// also writes cursor copy and dis = rsqrt(deg).
__global__ __launch_bounds__(1024) void scan_kernel(const int* __restrict__ deg,
                                                    int* __restrict__ off,
                                                    int* __restrict__ cur,
                                                    float* __restrict__ dis, int N) {
    __shared__ int sdata[1024];
    int t = threadIdx.x;
    int CH = (N + 1023) >> 10;
    int start = t * CH;
    int end = min(start + CH, N);
    int s = 0;
    for (int i = start; i < end; ++i) s += deg[i] - 1;
    sdata[t] = s;
    __syncthreads();
    for (int d = 1; d < 1024; d <<= 1) {
        int v = (t >= d) ? sdata[t - d] : 0;
        __syncthreads();
        sdata[t] += v;
        __syncthreads();
    }
    int run = (t == 0) ? 0 : sdata[t - 1];   // exclusive prefix
    for (int i = start; i < end; ++i) {
        off[i] = run;
        cur[i] = run;
        dis[i] = rsqrtf((float)deg[i]);
        run += deg[i] - 1;
    }
    if (t == 1023) off[N] = run;             // == E (later chunks empty)
}

__global__ __launch_bounds__(256) void fill_kernel(const int* __restrict__ row,
                                                   const int* __restrict__ col,
                                                   int* __restrict__ cur,
                                                   int* __restrict__ csr_src, int E) {
    int i = blockIdx.x * 256 + threadIdx.x;
    if (i < E) {
        int p = atomicAdd(&cur[col[i]], 1);
        csr_src[p] = row[i];
    }
}

// Y[M,TN] = X[M,128] @ W[128,TN].  Tile: 64 rows x TN cols, K-chunks of 32.
// As stored transposed (As[k][r]) so the compute loop does aligned float4 reads.
template<int TN>
__global__ __launch_bounds__(256) void gemm_kernel(const float* __restrict__ X,
                                                   const float* __restrict__ W,
                                                   float* __restrict__ Y, int M) {
    constexpr int K = 128, KC = 32, TM = 64;
    constexpr int CPT = TN / 16;                 // cols per thread: 8 (TN=128) / 4 (TN=64)
    __shared__ float As[KC][TM + 8];             // +8 pad keeps 16B align, breaks stride
    __shared__ float Bs[KC][TN];
    int tid = threadIdx.x;
    int row0 = blockIdx.x * TM;
    int tx = tid & 15, ty = tid >> 4;            // 16x16 thread grid
    float acc[4][CPT];
#pragma unroll
    for (int i = 0; i < 4; ++i)
#pragma unroll
        for (int j = 0; j < CPT; ++j) acc[i][j] = 0.0f;

    for (int k0 = 0; k0 < K; k0 += KC) {
        // load X chunk (64 rows x 32 k) as float4, store transposed
#pragma unroll
        for (int j = 0; j < 2; ++j) {
            int l = tid + 256 * j;               // 0..511
            int r = l >> 3;                      // row in tile (8 float4 per row)
            int kq = l & 7;
            int row = row0 + r;
            float4 v = make_float4(0.f, 0.f, 0.f, 0.f);
            if (row < M) v = *(const float4*)(X + (size_t)row * K + k0 + kq * 4);
            As[kq * 4 + 0][r] = v.x;
            As[kq * 4 + 1][r] = v.y;
            As[kq * 4 + 2][r] = v.z;
            As[kq * 4 + 3][r] = v.w;
        }
        // load W chunk (32 k x TN cols), row-major
#pragma unroll
        for (int j = 0; j < KC * TN / 1024; ++j) {
            int l = tid + 256 * j;
            int kk = l / (TN / 4);
            int cq = l % (TN / 4);
            *(float4*)&Bs[kk][cq * 4] = *(const float4*)(W + (size_t)(k0 + kk) * TN + cq * 4);
        }
        __syncthreads();
#pragma unroll
        for (int kk = 0; kk < KC; ++kk) {
            float4 av = *(const float4*)&As[kk][ty * 4];
            float a[4] = {av.x, av.y, av.z, av.w};
            float b[CPT];
#pragma unroll
            for (int q = 0; q < CPT / 4; ++q) {
                float4 bv = *(const float4*)&Bs[kk][tx * CPT + q * 4];
                b[q * 4 + 0] = bv.x; b[q * 4 + 1] = bv.y;
                b[q * 4 + 2] = bv.z; b[q * 4 + 3] = bv.w;
            }
#pragma unroll
            for (int i = 0; i < 4; ++i)
#pragma unroll
                for (int j = 0; j < CPT; ++j) acc[i][j] = fmaf(a[i], b[j], acc[i][j]);
        }
        __syncthreads();
    }
#pragma unroll
    for (int i = 0; i < 4; ++i) {
        int row = row0 + ty * 4 + i;
        if (row < M) {
#pragma unroll
            for (int q = 0; q < CPT / 4; ++q) {
                float4 v = make_float4(acc[i][q * 4], acc[i][q * 4 + 1],
                                       acc[i][q * 4 + 2], acc[i][q * 4 + 3]);
                *(float4*)(Y + (size_t)row * TN + tx * CPT + q * 4) = v;
            }
        }
    }
}

// out[v] = sum_{e: col=v} dis[src]*dis[v]*H[src] + dis[v]^2*H[v] + b, opt relu.
// One wave (64 lanes) per node; 4 nodes per 256-thread block.
template<int C, bool RELU>
__global__ __launch_bounds__(256) void agg_kernel(const float* __restrict__ H,
                                                  const int* __restrict__ off,
                                                  const int* __restrict__ src,
                                                  const float* __restrict__ dis,
                                                  const float* __restrict__ bias,
                                                  float* __restrict__ out, int N) {
    int node = blockIdx.x * 4 + (threadIdx.x >> 6);
    if (node >= N) return;
    int lane = threadIdx.x & 63;
    constexpr int F = C / 64;                    // floats per lane (2 or 1)
    float dv = dis[node];
    float acc[F];
    {
        const float* hp = H + (size_t)node * C + lane * F;
        float sw = dv * dv;
#pragma unroll
        for (int f = 0; f < F; ++f) acc[f] = sw * hp[f];
    }
    int e = off[node], e1 = off[node + 1];
    // 4 edges in flight for MLP latency hiding
    for (; e + 4 <= e1; e += 4) {
        int s0 = src[e + 0], s1 = src[e + 1], s2 = src[e + 2], s3 = src[e + 3];
        float w0 = dis[s0] * dv, w1 = dis[s1] * dv, w2 = dis[s2] * dv, w3 = dis[s3] * dv;
        const float* p0 = H + (size_t)s0 * C + lane * F;
        const float* p1 = H + (size_t)s1 * C + lane * F;
        const float* p2 = H + (size_t)s2 * C + lane * F;
        const float* p3 = H + (size_t)s3 * C + lane * F;
        if constexpr (F == 2) {
            float2 v0 = *(const float2*)p0, v1 = *(const float2*)p1;
            float2 v2 = *(const float2*)p2, v3 = *(const float2*)p3;
            acc[0] = fmaf(w0, v0.x, acc[0]); acc[1] = fmaf(w0, v0.y, acc[1]);
            acc[0] = fmaf(w1, v1.x, acc[0]); acc[1] = fmaf(w1, v1.y, acc[1]);
            acc[0] = fmaf(w2, v2.x, acc[0]); acc[1] = fmaf(w2, v2.y, acc[1]);
            acc[0] = fmaf(w3, v3.x, acc[0]); acc[1] = fmaf(w3, v3.y, acc[1]);
        } else {
            acc[0] = fmaf(w0, p0[0], acc[0]);
            acc[0] = fmaf(w1, p1[0], acc[0]);
            acc[0] = fmaf(w2, p2[0], acc[0]);
            acc[0] = fmaf(w3, p3[0], acc[0]);
        }
    }
    for (; e < e1; ++e) {
        int s = src[e];
        float w = dis[s] * dv;
        const float* p = H + (size_t)s * C + lane * F;
#pragma unroll
        for (int f = 0; f < F; ++f) acc[f] = fmaf(w, p[f], acc[f]);
    }
    float* op = out + (size_t)node * C + lane * F;
#pragma unroll
    for (int f = 0; f < F; ++f) {
        float v = acc[f] + bias[lane * F + f];
        op[f] = RELU ? fmaxf(v, 0.0f) : v;
    }
}

extern "C" void kernel_launch(void* const* d_in, const int* in_sizes, int n_in,
                              void* d_out, int out_size, void* d_ws, size_t ws_size,
                              hipStream_t stream) {
    const float* x  = (const float*)d_in[0];
    const int*   ei = (const int*)d_in[1];
    const float* W1 = (const float*)d_in[2];
    const float* b1 = (const float*)d_in[3];
    const float* W2 = (const float*)d_in[4];
    const float* b2 = (const float*)d_in[5];
    float* out = (float*)d_out;

    int N = in_sizes[0] / 128;
    int E = in_sizes[1] / 2;
    const int* row = ei;        // edge_index[0] = sources
    const int* col = ei + E;    // edge_index[1] = targets

    char* ws = (char*)d_ws;
    size_t o = 0;
    auto alloc = [&](size_t bytes) -> void* {
        void* p = ws + o;
        o = (o + bytes + 255) & ~(size_t)255;
        return p;
    };
    int*   deg = (int*)alloc((size_t)N * 4);
    int*   off = (int*)alloc((size_t)(N + 1) * 4);
    int*   cur = (int*)alloc((size_t)N * 4);
    float* dis = (float*)alloc((size_t)N * 4);
    int*   csr = (int*)alloc((size_t)E * 4);
    float* xw  = (float*)alloc((size_t)N * 128 * 4);
    float* h   = (float*)alloc((size_t)N * 128 * 4);
    float* hw2 = xw;   // reuse (layer-2 GEMM output, 64 cols)

    init_deg_kernel<<<(N + 255) / 256, 256, 0, stream>>>(deg, N);
    count_kernel<<<(E + 255) / 256, 256, 0, stream>>>(col, deg, E);
    scan_kernel<<<1, 1024, 0, stream>>>(deg, off, cur, dis, N);
    fill_kernel<<<(E + 255) / 256, 256, 0, stream>>>(row, col, cur, csr, E);

    gemm_kernel<128><<<(N + 63) / 64, 256, 0, stream>>>(x, W1, xw, N);
    agg_kernel<128, true><<<(N + 3) / 4, 256, 0, stream>>>(xw, off, csr, dis, b1, h, N);
    gemm_kernel<64><<<(N + 63) / 64, 256, 0, stream>>>(h, W2, hw2, N);
    agg_kernel<64, false><<<(N + 3) / 4, 256, 0, stream>>>(hw2, off, csr, dis, b2, out, N);
}

// Round 2
// 475.936 us; speedup vs baseline: 1.5896x; 1.5896x over previous
//
#include <hip/hip_runtime.h>

// GCN 2-layer forward: out = A( relu(A(X@W1)+b1) @ W2 ) + b2
// where A is sym-normalized adjacency with self loops.
// CSR build: count -> hierarchical scan (3 parallel kernels) -> fill.
// Each layer: LDS-tiled vector-fp32 GEMM + gather-aggregate (no float atomics).

__global__ __launch_bounds__(256) void init_deg_kernel(int* __restrict__ deg, int n) {
    int i = blockIdx.x * 256 + threadIdx.x;
    if (i < n) deg[i] = 1;   // self loop
}

__global__ __launch_bounds__(256) void count_kernel(const int* __restrict__ col,
                                                    int* __restrict__ deg, int E) {
    int i = blockIdx.x * 256 + threadIdx.x;
    if (i < E) atomicAdd(&deg[col[i]], 1);
}

// Phase 1: per-block sums of (deg[i]-1).
__global__ __launch_bounds__(256) void blocksum_kernel(const int* __restrict__ deg,
                                                       int* __restrict__ bsum, int N) {
    int i = blockIdx.x * 256 + threadIdx.x;
    int v = (i < N) ? deg[i] - 1 : 0;
#pragma unroll
    for (int o = 32; o > 0; o >>= 1) v += __shfl_down(v, o, 64);
    __shared__ int ws[4];
    if ((threadIdx.x & 63) == 0) ws[threadIdx.x >> 6] = v;
    __syncthreads();
    if (threadIdx.x == 0) bsum[blockIdx.x] = ws[0] + ws[1] + ws[2] + ws[3];
}

// Phase 2: single-block exclusive scan of <=1024 block sums; writes total to *offN.
__global__ __launch_bounds__(1024) void bscan_kernel(const int* __restrict__ bsum,
                                                     int* __restrict__ boff,
                                                     int* __restrict__ offN, int nb) {
    __shared__ int s[1024];
    int t = threadIdx.x;
    int v = (t < nb) ? bsum[t] : 0;
    s[t] = v;
    __syncthreads();
    for (int d = 1; d < 1024; d <<= 1) {
        int u = (t >= d) ? s[t - d] : 0;
        __syncthreads();
        s[t] += u;
        __syncthreads();
    }
    if (t < nb) boff[t] = s[t] - v;           // exclusive
    if (t == nb - 1) *offN = s[t];            // total = E
}

// Phase 3: per-block exclusive scan of (deg-1) + block offset -> off/cur/dis.
__global__ __launch_bounds__(256) void offsets_kernel(const int* __restrict__ deg,
                                                      const int* __restrict__ boff,
                                                      int* __restrict__ off,
                                                      int* __restrict__ cur,
                                                      float* __restrict__ dis, int N) {
    int i = blockIdx.x * 256 + threadIdx.x;
    int lane = threadIdx.x & 63;
    int w = threadIdx.x >> 6;
    int d = (i < N) ? deg[i] - 1 : 0;
    int v = d;
#pragma unroll
    for (int o = 1; o < 64; o <<= 1) {
        int u = __shfl_up(v, o, 64);
        if (lane >= o) v += u;
    }
    __shared__ int ws[4];
    __shared__ int wo[4];
    if (lane == 63) ws[w] = v;
    __syncthreads();
    if (threadIdx.x == 0) {
        int r = 0;
#pragma unroll
        for (int k = 0; k < 4; ++k) { wo[k] = r; r += ws[k]; }
    }
    __syncthreads();
    if (i < N) {
        int excl = boff[blockIdx.x] + wo[w] + v - d;
        off[i] = excl;
        cur[i] = excl;
        dis[i] = rsqrtf((float)deg[i]);
    }
}

__global__ __launch_bounds__(256) void fill_kernel(const int* __restrict__ row,
                                                   const int* __restrict__ col,
                                                   int* __restrict__ cur,
                                                   int* __restrict__ csr_src, int E) {
    int i = blockIdx.x * 256 + threadIdx.x;
    if (i < E) {
        int p = atomicAdd(&cur[col[i]], 1);
        csr_src[p] = row[i];
    }
}

// Y[M,TN] = X[M,128] @ W[128,TN].  Tile: 64 rows x TN cols, K-chunks of 32.
// As stored transposed (As[k][r]) so the compute loop does aligned float4 reads.
template<int TN>
__global__ __launch_bounds__(256) void gemm_kernel(const float* __restrict__ X,
                                                   const float* __restrict__ W,
                                                   float* __restrict__ Y, int M) {
    constexpr int K = 128, KC = 32, TM = 64;
    constexpr int CPT = TN / 16;                 // cols per thread: 8 (TN=128) / 4 (TN=64)
    __shared__ float As[KC][TM + 8];
    __shared__ float Bs[KC][TN];
    int tid = threadIdx.x;
    int row0 = blockIdx.x * TM;
    int tx = tid & 15, ty = tid >> 4;            // 16x16 thread grid
    float acc[4][CPT];
#pragma unroll
    for (int i = 0; i < 4; ++i)
#pragma unroll
        for (int j = 0; j < CPT; ++j) acc[i][j] = 0.0f;

    for (int k0 = 0; k0 < K; k0 += KC) {
#pragma unroll
        for (int j = 0; j < 2; ++j) {
            int l = tid + 256 * j;               // 0..511
            int r = l >> 3;
            int kq = l & 7;
            int row = row0 + r;
            float4 v = make_float4(0.f, 0.f, 0.f, 0.f);
            if (row < M) v = *(const float4*)(X + (size_t)row * K + k0 + kq * 4);
            As[kq * 4 + 0][r] = v.x;
            As[kq * 4 + 1][r] = v.y;
            As[kq * 4 + 2][r] = v.z;
            As[kq * 4 + 3][r] = v.w;
        }
#pragma unroll
        for (int j = 0; j < KC * TN / 1024; ++j) {
            int l = tid + 256 * j;
            int kk = l / (TN / 4);
            int cq = l % (TN / 4);
            *(float4*)&Bs[kk][cq * 4] = *(const float4*)(W + (size_t)(k0 + kk) * TN + cq * 4);
        }
        __syncthreads();
#pragma unroll
        for (int kk = 0; kk < KC; ++kk) {
            float4 av = *(const float4*)&As[kk][ty * 4];
            float a[4] = {av.x, av.y, av.z, av.w};
            float b[CPT];
#pragma unroll
            for (int q = 0; q < CPT / 4; ++q) {
                float4 bv = *(const float4*)&Bs[kk][tx * CPT + q * 4];
                b[q * 4 + 0] = bv.x; b[q * 4 + 1] = bv.y;
                b[q * 4 + 2] = bv.z; b[q * 4 + 3] = bv.w;
            }
#pragma unroll
            for (int i = 0; i < 4; ++i)
#pragma unroll
                for (int j = 0; j < CPT; ++j) acc[i][j] = fmaf(a[i], b[j], acc[i][j]);
        }
        __syncthreads();
    }
#pragma unroll
    for (int i = 0; i < 4; ++i) {
        int row = row0 + ty * 4 + i;
        if (row < M) {
#pragma unroll
            for (int q = 0; q < CPT / 4; ++q) {
                float4 v = make_float4(acc[i][q * 4], acc[i][q * 4 + 1],
                                       acc[i][q * 4 + 2], acc[i][q * 4 + 3]);
                *(float4*)(Y + (size_t)row * TN + tx * CPT + q * 4) = v;
            }
        }
    }
}

// out[v] = sum_{e: col=v} dis[src]*dis[v]*H[src] + dis[v]^2*H[v] + b, opt relu.
// One wave (64 lanes) per node; 4 nodes per 256-thread block.
template<int C, bool RELU>
__global__ __launch_bounds__(256) void agg_kernel(const float* __restrict__ H,
                                                  const int* __restrict__ off,
                                                  const int* __restrict__ src,
                                                  const float* __restrict__ dis,
                                                  const float* __restrict__ bias,
                                                  float* __restrict__ out, int N) {
    int node = blockIdx.x * 4 + (threadIdx.x >> 6);
    if (node >= N) return;
    int lane = threadIdx.x & 63;
    constexpr int F = C / 64;                    // floats per lane (2 or 1)
    float dv = dis[node];
    float acc[F];
    {
        const float* hp = H + (size_t)node * C + lane * F;
        float sw = dv * dv;
#pragma unroll
        for (int f = 0; f < F; ++f) acc[f] = sw * hp[f];
    }
    int e = off[node], e1 = off[node + 1];
    for (; e + 4 <= e1; e += 4) {
        int s0 = src[e + 0], s1 = src[e + 1], s2 = src[e + 2], s3 = src[e + 3];
        float w0 = dis[s0] * dv, w1 = dis[s1] * dv, w2 = dis[s2] * dv, w3 = dis[s3] * dv;
        const float* p0 = H + (size_t)s0 * C + lane * F;
        const float* p1 = H + (size_t)s1 * C + lane * F;
        const float* p2 = H + (size_t)s2 * C + lane * F;
        const float* p3 = H + (size_t)s3 * C + lane * F;
        if constexpr (F == 2) {
            float2 v0 = *(const float2*)p0, v1 = *(const float2*)p1;
            float2 v2 = *(const float2*)p2, v3 = *(const float2*)p3;
            acc[0] = fmaf(w0, v0.x, acc[0]); acc[1] = fmaf(w0, v0.y, acc[1]);
            acc[0] = fmaf(w1, v1.x, acc[0]); acc[1] = fmaf(w1, v1.y, acc[1]);
            acc[0] = fmaf(w2, v2.x, acc[0]); acc[1] = fmaf(w2, v2.y, acc[1]);
            acc[0] = fmaf(w3, v3.x, acc[0]); acc[1] = fmaf(w3, v3.y, acc[1]);
        } else {
            acc[0] = fmaf(w0, p0[0], acc[0]);
            acc[0] = fmaf(w1, p1[0], acc[0]);
            acc[0] = fmaf(w2, p2[0], acc[0]);
            acc[0] = fmaf(w3, p3[0], acc[0]);
        }
    }
    for (; e < e1; ++e) {
        int s = src[e];
        float w = dis[s] * dv;
        const float* p = H + (size_t)s * C + lane * F;
#pragma unroll
        for (int f = 0; f < F; ++f) acc[f] = fmaf(w, p[f], acc[f]);
    }
    float* op = out + (size_t)node * C + lane * F;
#pragma unroll
    for (int f = 0; f < F; ++f) {
        float v = acc[f] + bias[lane * F + f];
        op[f] = RELU ? fmaxf(v, 0.0f) : v;
    }
}

extern "C" void kernel_launch(void* const* d_in, const int* in_sizes, int n_in,
                              void* d_out, int out_size, void* d_ws, size_t ws_size,
                              hipStream_t stream) {
    const float* x  = (const float*)d_in[0];
    const int*   ei = (const int*)d_in[1];
    const float* W1 = (const float*)d_in[2];
    const float* b1 = (const float*)d_in[3];
    const float* W2 = (const float*)d_in[4];
    const float* b2 = (const float*)d_in[5];
    float* out = (float*)d_out;

    int N = in_sizes[0] / 128;
    int E = in_sizes[1] / 2;
    const int* row = ei;        // edge_index[0] = sources
    const int* col = ei + E;    // edge_index[1] = targets
    int nblk = (N + 255) / 256;

    char* ws = (char*)d_ws;
    size_t o = 0;
    auto alloc = [&](size_t bytes) -> void* {
        void* p = ws + o;
        o = (o + bytes + 255) & ~(size_t)255;
        return p;
    };
    int*   deg  = (int*)alloc((size_t)N * 4);
    int*   off  = (int*)alloc((size_t)(N + 1) * 4);
    int*   cur  = (int*)alloc((size_t)N * 4);
    float* dis  = (float*)alloc((size_t)N * 4);
    int*   csr  = (int*)alloc((size_t)E * 4);
    int*   bsum = (int*)alloc((size_t)nblk * 4);
    int*   boff = (int*)alloc((size_t)nblk * 4);
    float* xw   = (float*)alloc((size_t)N * 128 * 4);
    float* h    = (float*)alloc((size_t)N * 128 * 4);
    float* hw2  = xw;   // reuse (layer-2 GEMM output, 64 cols)

    init_deg_kernel<<<nblk, 256, 0, stream>>>(deg, N);
    count_kernel<<<(E + 255) / 256, 256, 0, stream>>>(col, deg, E);
    blocksum_kernel<<<nblk, 256, 0, stream>>>(deg, bsum, N);
    bscan_kernel<<<1, 1024, 0, stream>>>(bsum, boff, &off[N], nblk);
    offsets_kernel<<<nblk, 256, 0, stream>>>(deg, boff, off, cur, dis, N);
    fill_kernel<<<(E + 255) / 256, 256, 0, stream>>>(row, col, cur, csr, E);

    gemm_kernel<128><<<(N + 63) / 64, 256, 0, stream>>>(x, W1, xw, N);
    agg_kernel<128, true><<<(N + 3) / 4, 256, 0, stream>>>(xw, off, csr, dis, b1, h, N);
    gemm_kernel<64><<<(N + 63) / 64, 256, 0, stream>>>(h, W2, hw2, N);
    agg_kernel<64, false><<<(N + 3) / 4, 256, 0, stream>>>(hw2, off, csr, dis, b2, out, N);
}